// Round 6
// baseline (325.932 us; speedup 1.0000x reference)
//
#include <hip/hip_runtime.h>
#include <stdint.h>
#include <stddef.h>

// RBF kernel: out[i][j] = exp(-max(||x_i||^2 + ||x1_j||^2 - 2*x_i.x1_j, 0) / 1.0)
// N = M = 8192, K = 512, fp32 in/out.
//
// Round 6 = Round 5 (MX-fp8, XOR-swizzle, pipelined vmcnt K-loop) + operand-
// swapped MFMA: acc[j][i] = mfma(bg[j], af[i], .) puts x-rows in the lane&15
// dim and x1-cols in the reg dim -> each lane holds 4 CONSECUTIVE out-cols.
// Epilogue: 16 dwordx4 nontemporal stores/thread (was 64 dword stores),
// float4 norm loads. A/B operand layouts are identical so fragment loading
// is untouched.

#define NROWS 8192
#define DIMK  512
#define BM    128
#define BN    128
#define BKB   128              // K-bytes (= elements) per fp8 tile
#define KT    (DIMK / BKB)     // 4

typedef __bf16 bf16x8 __attribute__((ext_vector_type(8)));
typedef int    i32x8  __attribute__((ext_vector_type(8)));
typedef int    i32x4  __attribute__((ext_vector_type(4)));
typedef float  f32x4  __attribute__((ext_vector_type(4)));

#define AS1 __attribute__((address_space(1)))
#define AS3 __attribute__((address_space(3)))

// raw waits/barrier — keep prefetch DMA in flight across barriers
#define WAITV(n) asm volatile("s_waitcnt vmcnt(" #n ")" ::: "memory")
#define WAITL()  asm volatile("s_waitcnt lgkmcnt(0)" ::: "memory")
#define BAR()    asm volatile("s_barrier" ::: "memory")

__device__ __forceinline__ uint32_t f2bf(float f) {
    uint32_t u = __float_as_uint(f);
    return (u + 0x7FFFu + ((u >> 16) & 1u)) >> 16;
}

// pack 4 floats -> 4 e4m3 bytes via HW converter (RNE, saturating)
__device__ __forceinline__ uint32_t pk_fp8x4(float a, float b, float c, float d) {
    int w = __builtin_amdgcn_cvt_pk_fp8_f32(a, b, 0, false);   // bytes 0,1
    w     = __builtin_amdgcn_cvt_pk_fp8_f32(c, d, w, true);    // bytes 2,3
    return (uint32_t)w;
}

// assemble a 32B MFMA fragment from two (swizzle-permuted) 16B LDS chunks
__device__ __forceinline__ i32x8 ld_frag(const uint8_t* base, int c_lo, int c_hi) {
    i32x4 lo = *(const i32x4*)(base + c_lo);
    i32x4 hi = *(const i32x4*)(base + c_hi);
    i32x8 r;
    r[0] = lo[0]; r[1] = lo[1]; r[2] = lo[2]; r[3] = lo[3];
    r[4] = hi[0]; r[5] = hi[1]; r[6] = hi[2]; r[7] = hi[3];
    return r;
}

// ---------------------------------------------------------------- precast ---
__global__ __launch_bounds__(256) void precast_fp8(
    const float* __restrict__ x, const float* __restrict__ x1,
    uint8_t* __restrict__ xf, uint8_t* __restrict__ x1f,
    float* __restrict__ xsq, float* __restrict__ x1sq)
{
    const int w    = threadIdx.x >> 6;
    const int lane = threadIdx.x & 63;
    const int row  = blockIdx.x * 4 + w;
    const float* src;
    uint8_t* dstb;
    float* dsts;
    if (blockIdx.y == 0) { src = x  + (size_t)row * DIMK; dstb = xf  + (size_t)row * DIMK; dsts = xsq  + row; }
    else                 { src = x1 + (size_t)row * DIMK; dstb = x1f + (size_t)row * DIMK; dsts = x1sq + row; }

    float4 v0 = ((const float4*)src)[lane * 2];
    float4 v1 = ((const float4*)src)[lane * 2 + 1];
    float s = v0.x * v0.x + v0.y * v0.y + v0.z * v0.z + v0.w * v0.w
            + v1.x * v1.x + v1.y * v1.y + v1.z * v1.z + v1.w * v1.w;

    uint2 p;
    p.x = pk_fp8x4(v0.x, v0.y, v0.z, v0.w);
    p.y = pk_fp8x4(v1.x, v1.y, v1.z, v1.w);
    ((uint2*)dstb)[lane] = p;

    #pragma unroll
    for (int off = 32; off > 0; off >>= 1) s += __shfl_down(s, off);
    if (lane == 0) *dsts = s;
}

// norms only (fallback path)
__global__ __launch_bounds__(256) void norms_only(
    const float* __restrict__ x, const float* __restrict__ x1,
    float* __restrict__ xsq, float* __restrict__ x1sq)
{
    const int row = blockIdx.x;
    const float* src = (blockIdx.y == 0) ? x + (size_t)row * DIMK : x1 + (size_t)row * DIMK;
    float* dsts      = (blockIdx.y == 0) ? xsq + row : x1sq + row;
    const int t = threadIdx.x;
    float2 v = ((const float2*)src)[t];
    float s = v.x * v.x + v.y * v.y;
    #pragma unroll
    for (int off = 32; off > 0; off >>= 1) s += __shfl_down(s, off);
    __shared__ float red[4];
    if ((t & 63) == 0) red[t >> 6] = s;
    __syncthreads();
    if (t == 0) *dsts = red[0] + red[1] + red[2] + red[3];
}

// ------------------------------------------- main GEMM (MX-fp8, pipelined) ---
// Wait ladder (8 DMA loads per stage, vmcnt completes in order — m135):
//   prologue: stage(0->buf0), stage(1->buf1)            [16 outstanding]
//   kt=0: vmcnt(8)+bar | reads | lgkm+bar | stage(2->buf0) | mfma
//   kt=1: vmcnt(8)+bar | reads | lgkm+bar | stage(3->buf1) | mfma
//   kt=2: vmcnt(8)+bar | reads |                           | mfma
//   kt=3: vmcnt(0)+bar | reads |                           | mfma
// Epilogue vmem strictly after the last wait so vmcnt bookkeeping is exact.
//
// MFMA operand swap: acc[j][i] = mfma(bg[j], af[i], acc[j][i]) so
// D[m=x1 col][n=x row]; lane holds out-row = lrow (fixed per tm) and
// out-cols = (lane>>4)*4 + reg (4 consecutive) -> dwordx4 stores.
__global__ __launch_bounds__(256) void rbf_mfma_mxfp8(
    const uint8_t* __restrict__ Xf, const uint8_t* __restrict__ X1f,
    const float* __restrict__ xsq, const float* __restrict__ x1sq,
    float* __restrict__ out)
{
    __shared__ uint8_t As[2][BM * BKB];   // 2 x 16 KB
    __shared__ uint8_t Bs[2][BN * BKB];   // 2 x 16 KB

    const int t    = threadIdx.x;
    const int bm   = blockIdx.x;
    const int bn   = blockIdx.y;
    const int lane = t & 63;
    const int w    = t >> 6;
    const int wm   = w >> 1;
    const int wn   = w & 1;

    const int srow   = t >> 3;                       // 0..31
    const int schunk = (t & 7) ^ (srow & 7);         // XOR-swizzled global chunk
    const uint8_t* gA = Xf  + (size_t)(bm * BM + srow) * DIMK + schunk * 16;
    const uint8_t* gB = X1f + (size_t)(bn * BN + srow) * DIMK + schunk * 16;

    f32x4 acc[4][4];   // acc[tn][tm]
    #pragma unroll
    for (int i = 0; i < 4; ++i)
        #pragma unroll
        for (int j = 0; j < 4; ++j)
            acc[i][j] = f32x4{0.f, 0.f, 0.f, 0.f};

    // Operand layout (A and B identical): row = lane&15, kbyte = q*32+0..31.
    // Swizzle: kbyte chunk c of row r lives at LDS chunk c^(r&7).
    const int lrow = lane & 15;
    const int q    = lane >> 4;
    const int s    = lrow & 7;
    const int c_lo = ((2 * q)     ^ s) * 16;
    const int c_hi = ((2 * q + 1) ^ s) * 16;
    int roff[4];
    #pragma unroll
    for (int i = 0; i < 4; ++i) roff[i] = (i * 16 + lrow) * BKB;

    auto stage = [&](int kt, int b) {
        const uint8_t* ga = gA + kt * BKB;
        const uint8_t* gb = gB + kt * BKB;
        uint8_t* la = &As[b][t * 16];
        uint8_t* lb = &Bs[b][t * 16];
        #pragma unroll
        for (int c = 0; c < 4; ++c) {
            __builtin_amdgcn_global_load_lds((AS1 void*)(ga + (size_t)c * 32 * DIMK),
                                             (AS3 void*)(la + c * 4096), 16, 0, 0);
            __builtin_amdgcn_global_load_lds((AS1 void*)(gb + (size_t)c * 32 * DIMK),
                                             (AS3 void*)(lb + c * 4096), 16, 0, 0);
        }
    };

    auto read_frags = [&](int b, i32x8* af, i32x8* bg) {
        #pragma unroll
        for (int i = 0; i < 4; ++i)
            af[i] = ld_frag(&As[b][wm * 64 * BKB + roff[i]], c_lo, c_hi);
        #pragma unroll
        for (int i = 0; i < 4; ++i)
            bg[i] = ld_frag(&Bs[b][wn * 64 * BKB + roff[i]], c_lo, c_hi);
    };

    // swapped operands: A = bg[j] (x1 rows -> out-col in reg dim),
    //                   B = af[i] (x rows -> out-row in lane&15 dim)
    auto do_mfma = [&](const i32x8* af, const i32x8* bg) {
        #pragma unroll
        for (int j = 0; j < 4; ++j)
            #pragma unroll
            for (int i = 0; i < 4; ++i)
                acc[j][i] = __builtin_amdgcn_mfma_scale_f32_16x16x128_f8f6f4(
                    bg[j], af[i], acc[j][i],
                    0, 0,                    // cbsz=0 (fp8 e4m3), blgp=0 (fp8 e4m3)
                    0, 0x7F7F7F7F,           // opselA, scaleA (e8m0 127 = 2^0)
                    0, 0x7F7F7F7F);          // opselB, scaleB
    };

    i32x8 af[4], bg[4];

    stage(0, 0);
    stage(1, 1);                           // 16 outstanding

    // kt = 0
    WAITV(8); BAR();
    read_frags(0, af, bg);
    WAITL(); BAR();
    stage(2, 0);
    do_mfma(af, bg);

    // kt = 1
    WAITV(8); BAR();
    read_frags(1, af, bg);
    WAITL(); BAR();
    stage(3, 1);
    do_mfma(af, bg);

    // kt = 2
    WAITV(8); BAR();
    read_frags(0, af, bg);
    do_mfma(af, bg);

    // kt = 3
    WAITV(0); BAR();
    read_frags(1, af, bg);
    do_mfma(af, bg);

    // epilogue (transposed acc): out-row = bm*128+wm*64+tm*16+lrow,
    // out-col base = bn*128+wn*64+tn*16+(lane>>4)*4, reg r -> col base + r.
    const int orow = bm * BM + wm * 64 + lrow;
    const int ocol = bn * BN + wn * 64 + q * 4;
    float xs[4];
    f32x4 x1v[4];
    #pragma unroll
    for (int tm = 0; tm < 4; ++tm) xs[tm] = xsq[orow + tm * 16];
    #pragma unroll
    for (int tn = 0; tn < 4; ++tn) x1v[tn] = *(const f32x4*)&x1sq[ocol + tn * 16];

    #pragma unroll
    for (int tm = 0; tm < 4; ++tm) {
        float* orow_p = out + (size_t)(orow + tm * 16) * NROWS;
        #pragma unroll
        for (int tn = 0; tn < 4; ++tn) {
            f32x4 a = acc[tn][tm];
            f32x4 ev;
            #pragma unroll
            for (int r = 0; r < 4; ++r) {
                float d = fmaxf(xs[tm] + x1v[tn][r] - 2.0f * a[r], 0.0f);
                ev[r] = __expf(-d);
            }
            __builtin_nontemporal_store(ev, (f32x4*)(orow_p + ocol + tn * 16));
        }
    }
}

// Fallback GEMM (ws too small for fp8 copies): inline fp32->bf16 cast staging.
__global__ __launch_bounds__(256) void rbf_mfma_inline(
    const float* __restrict__ X, const float* __restrict__ X1,
    const float* __restrict__ xsq, const float* __restrict__ x1sq,
    float* __restrict__ out)
{
    __shared__ uint16_t As[BM * 32];
    __shared__ uint16_t Bs[BN * 32];

    const int t    = threadIdx.x;
    const int bm   = blockIdx.x;
    const int bn   = blockIdx.y;
    const int lane = t & 63;
    const int w    = t >> 6;
    const int wm   = w >> 1;
    const int wn   = w & 1;

    f32x4 acc[4][4];
    #pragma unroll
    for (int i = 0; i < 4; ++i)
        #pragma unroll
        for (int j = 0; j < 4; ++j)
            acc[i][j] = f32x4{0.f, 0.f, 0.f, 0.f};

    const int lrow = lane & 15;
    const int kq   = (lane >> 4) * 8;
    int aoff[4], boff[4];
    #pragma unroll
    for (int i = 0; i < 4; ++i) {
        aoff[i] = (wm * 64 + i * 16 + lrow) * 32 + kq;
        boff[i] = (wn * 64 + i * 16 + lrow) * 32 + kq;
    }

    #pragma unroll 1
    for (int kt = 0; kt < DIMK / 32; ++kt) {
        #pragma unroll
        for (int i = 0; i < 4; ++i) {
            const int g   = t + i * 256;
            const int row = g >> 3;
            const int c4  = (g & 7) * 4;
            float4 va = *(const float4*)&X [(size_t)(bm * BM + row) * DIMK + kt * 32 + c4];
            float4 vb = *(const float4*)&X1[(size_t)(bn * BN + row) * DIMK + kt * 32 + c4];
            uint2 pa, pb;
            pa.x = f2bf(va.x) | (f2bf(va.y) << 16);
            pa.y = f2bf(va.z) | (f2bf(va.w) << 16);
            pb.x = f2bf(vb.x) | (f2bf(vb.y) << 16);
            pb.y = f2bf(vb.z) | (f2bf(vb.w) << 16);
            *(uint2*)&As[g * 4] = pa;
            *(uint2*)&Bs[g * 4] = pb;
        }
        __syncthreads();

        bf16x8 af[4], bg[4];
        #pragma unroll
        for (int i = 0; i < 4; ++i) af[i] = *(const bf16x8*)&As[aoff[i]];
        #pragma unroll
        for (int i = 0; i < 4; ++i) bg[i] = *(const bf16x8*)&Bs[boff[i]];
        #pragma unroll
        for (int i = 0; i < 4; ++i)
            #pragma unroll
            for (int j = 0; j < 4; ++j)
                acc[i][j] = __builtin_amdgcn_mfma_f32_16x16x32_bf16(af[i], bg[j], acc[i][j], 0, 0, 0);
        __syncthreads();
    }

    const int row0 = bm * BM + wm * 64 + (lane >> 4) * 4;
    const int col0 = bn * BN + wn * 64 + lrow;
    float xs[4][4], x1s[4];
    #pragma unroll
    for (int tm = 0; tm < 4; ++tm)
        #pragma unroll
        for (int r = 0; r < 4; ++r) xs[tm][r] = xsq[row0 + tm * 16 + r];
    #pragma unroll
    for (int tn = 0; tn < 4; ++tn) x1s[tn] = x1sq[col0 + tn * 16];

    #pragma unroll
    for (int tm = 0; tm < 4; ++tm)
        #pragma unroll
        for (int tn = 0; tn < 4; ++tn)
            #pragma unroll
            for (int r = 0; r < 4; ++r) {
                const int row = row0 + tm * 16 + r;
                const int col = col0 + tn * 16;
                float d = xs[tm][r] + x1s[tn] - 2.0f * acc[tm][tn][r];
                d = fmaxf(d, 0.0f);
                out[(size_t)row * NROWS + col] = __expf(-d);
            }
}

// ------------------------------------------------------------------ launch ---
extern "C" void kernel_launch(void* const* d_in, const int* in_sizes, int n_in,
                              void* d_out, int out_size, void* d_ws, size_t ws_size,
                              hipStream_t stream)
{
    const float* x  = (const float*)d_in[0];
    const float* x1 = (const float*)d_in[1];
    float* out = (float*)d_out;

    const size_t f8_bytes  = (size_t)NROWS * DIMK;                       // 4 MB each
    const size_t need_full = 2 * f8_bytes + 2 * (size_t)NROWS * sizeof(float);

    dim3 gridG(NROWS / BM, NROWS / BN);   // 64 x 64 blocks

    if (ws_size >= need_full) {
        uint8_t* xf   = (uint8_t*)d_ws;
        uint8_t* x1f  = xf + f8_bytes;
        float*   xsq  = (float*)((char*)d_ws + 2 * f8_bytes);
        float*   x1sq = xsq + NROWS;
        precast_fp8<<<dim3(NROWS / 4, 2), 256, 0, stream>>>(x, x1, xf, x1f, xsq, x1sq);
        rbf_mfma_mxfp8<<<gridG, 256, 0, stream>>>(xf, x1f, xsq, x1sq, out);
    } else {
        float* xsq  = (float*)d_ws;       // 64 KB fallback
        float* x1sq = xsq + NROWS;
        norms_only<<<dim3(NROWS, 2), 256, 0, stream>>>(x, x1, xsq, x1sq);
        rbf_mfma_inline<<<gridG, 256, 0, stream>>>(x, x1, xsq, x1sq, out);
    }
}

// Round 7
// 312.020 us; speedup vs baseline: 1.0446x; 1.0446x over previous
//
#include <hip/hip_runtime.h>
#include <stdint.h>
#include <stddef.h>

// RBF kernel: out[i][j] = exp(-max(||x_i||^2 + ||x1_j||^2 - 2*x_i.x1_j, 0) / 1.0)
// N = M = 8192, K = 512, fp32 in/out.
//
// Round 7 = Round 6 minus nontemporal stores (single-variable change).
// Evidence: both NT rounds regressed (R3 +5us scalar-NT, R6 +21.6us x4-NT);
// nt bypasses L2 write-back merging -> partial-line writes to HBM. Normal
// stores let L2 absorb/stream the 268 MB output at ~6.3 TB/s.
// Kept from R6: operand-swapped MFMA (acc[j][i] = mfma(bg[j], af[i], .)) so
// each lane holds 4 consecutive out-cols -> 16 dwordx4 stores/thread.

#define NROWS 8192
#define DIMK  512
#define BM    128
#define BN    128
#define BKB   128              // K-bytes (= elements) per fp8 tile
#define KT    (DIMK / BKB)     // 4

typedef __bf16 bf16x8 __attribute__((ext_vector_type(8)));
typedef int    i32x8  __attribute__((ext_vector_type(8)));
typedef int    i32x4  __attribute__((ext_vector_type(4)));
typedef float  f32x4  __attribute__((ext_vector_type(4)));

#define AS1 __attribute__((address_space(1)))
#define AS3 __attribute__((address_space(3)))

// raw waits/barrier — keep prefetch DMA in flight across barriers
#define WAITV(n) asm volatile("s_waitcnt vmcnt(" #n ")" ::: "memory")
#define WAITL()  asm volatile("s_waitcnt lgkmcnt(0)" ::: "memory")
#define BAR()    asm volatile("s_barrier" ::: "memory")

__device__ __forceinline__ uint32_t f2bf(float f) {
    uint32_t u = __float_as_uint(f);
    return (u + 0x7FFFu + ((u >> 16) & 1u)) >> 16;
}

// pack 4 floats -> 4 e4m3 bytes via HW converter (RNE, saturating)
__device__ __forceinline__ uint32_t pk_fp8x4(float a, float b, float c, float d) {
    int w = __builtin_amdgcn_cvt_pk_fp8_f32(a, b, 0, false);   // bytes 0,1
    w     = __builtin_amdgcn_cvt_pk_fp8_f32(c, d, w, true);    // bytes 2,3
    return (uint32_t)w;
}

// assemble a 32B MFMA fragment from two (swizzle-permuted) 16B LDS chunks
__device__ __forceinline__ i32x8 ld_frag(const uint8_t* base, int c_lo, int c_hi) {
    i32x4 lo = *(const i32x4*)(base + c_lo);
    i32x4 hi = *(const i32x4*)(base + c_hi);
    i32x8 r;
    r[0] = lo[0]; r[1] = lo[1]; r[2] = lo[2]; r[3] = lo[3];
    r[4] = hi[0]; r[5] = hi[1]; r[6] = hi[2]; r[7] = hi[3];
    return r;
}

// ---------------------------------------------------------------- precast ---
__global__ __launch_bounds__(256) void precast_fp8(
    const float* __restrict__ x, const float* __restrict__ x1,
    uint8_t* __restrict__ xf, uint8_t* __restrict__ x1f,
    float* __restrict__ xsq, float* __restrict__ x1sq)
{
    const int w    = threadIdx.x >> 6;
    const int lane = threadIdx.x & 63;
    const int row  = blockIdx.x * 4 + w;
    const float* src;
    uint8_t* dstb;
    float* dsts;
    if (blockIdx.y == 0) { src = x  + (size_t)row * DIMK; dstb = xf  + (size_t)row * DIMK; dsts = xsq  + row; }
    else                 { src = x1 + (size_t)row * DIMK; dstb = x1f + (size_t)row * DIMK; dsts = x1sq + row; }

    float4 v0 = ((const float4*)src)[lane * 2];
    float4 v1 = ((const float4*)src)[lane * 2 + 1];
    float s = v0.x * v0.x + v0.y * v0.y + v0.z * v0.z + v0.w * v0.w
            + v1.x * v1.x + v1.y * v1.y + v1.z * v1.z + v1.w * v1.w;

    uint2 p;
    p.x = pk_fp8x4(v0.x, v0.y, v0.z, v0.w);
    p.y = pk_fp8x4(v1.x, v1.y, v1.z, v1.w);
    ((uint2*)dstb)[lane] = p;

    #pragma unroll
    for (int off = 32; off > 0; off >>= 1) s += __shfl_down(s, off);
    if (lane == 0) *dsts = s;
}

// norms only (fallback path)
__global__ __launch_bounds__(256) void norms_only(
    const float* __restrict__ x, const float* __restrict__ x1,
    float* __restrict__ xsq, float* __restrict__ x1sq)
{
    const int row = blockIdx.x;
    const float* src = (blockIdx.y == 0) ? x + (size_t)row * DIMK : x1 + (size_t)row * DIMK;
    float* dsts      = (blockIdx.y == 0) ? xsq + row : x1sq + row;
    const int t = threadIdx.x;
    float2 v = ((const float2*)src)[t];
    float s = v.x * v.x + v.y * v.y;
    #pragma unroll
    for (int off = 32; off > 0; off >>= 1) s += __shfl_down(s, off);
    __shared__ float red[4];
    if ((t & 63) == 0) red[t >> 6] = s;
    __syncthreads();
    if (t == 0) *dsts = red[0] + red[1] + red[2] + red[3];
}

// ------------------------------------------- main GEMM (MX-fp8, pipelined) ---
// Wait ladder (8 DMA loads per stage, vmcnt completes in order — m135):
//   prologue: stage(0->buf0), stage(1->buf1)            [16 outstanding]
//   kt=0: vmcnt(8)+bar | reads | lgkm+bar | stage(2->buf0) | mfma
//   kt=1: vmcnt(8)+bar | reads | lgkm+bar | stage(3->buf1) | mfma
//   kt=2: vmcnt(8)+bar | reads |                           | mfma
//   kt=3: vmcnt(0)+bar | reads |                           | mfma
// Epilogue vmem strictly after the last wait so vmcnt bookkeeping is exact.
//
// MFMA operand swap: acc[j][i] = mfma(bg[j], af[i], acc[j][i]) so
// D[m=x1 col][n=x row]; lane holds out-row = lrow (fixed per tm) and
// out-cols = (lane>>4)*4 + reg (4 consecutive) -> dwordx4 stores.
__global__ __launch_bounds__(256) void rbf_mfma_mxfp8(
    const uint8_t* __restrict__ Xf, const uint8_t* __restrict__ X1f,
    const float* __restrict__ xsq, const float* __restrict__ x1sq,
    float* __restrict__ out)
{
    __shared__ uint8_t As[2][BM * BKB];   // 2 x 16 KB
    __shared__ uint8_t Bs[2][BN * BKB];   // 2 x 16 KB

    const int t    = threadIdx.x;
    const int bm   = blockIdx.x;
    const int bn   = blockIdx.y;
    const int lane = t & 63;
    const int w    = t >> 6;
    const int wm   = w >> 1;
    const int wn   = w & 1;

    const int srow   = t >> 3;                       // 0..31
    const int schunk = (t & 7) ^ (srow & 7);         // XOR-swizzled global chunk
    const uint8_t* gA = Xf  + (size_t)(bm * BM + srow) * DIMK + schunk * 16;
    const uint8_t* gB = X1f + (size_t)(bn * BN + srow) * DIMK + schunk * 16;

    f32x4 acc[4][4];   // acc[tn][tm]
    #pragma unroll
    for (int i = 0; i < 4; ++i)
        #pragma unroll
        for (int j = 0; j < 4; ++j)
            acc[i][j] = f32x4{0.f, 0.f, 0.f, 0.f};

    // Operand layout (A and B identical): row = lane&15, kbyte = q*32+0..31.
    // Swizzle: kbyte chunk c of row r lives at LDS chunk c^(r&7).
    const int lrow = lane & 15;
    const int q    = lane >> 4;
    const int s    = lrow & 7;
    const int c_lo = ((2 * q)     ^ s) * 16;
    const int c_hi = ((2 * q + 1) ^ s) * 16;
    int roff[4];
    #pragma unroll
    for (int i = 0; i < 4; ++i) roff[i] = (i * 16 + lrow) * BKB;

    auto stage = [&](int kt, int b) {
        const uint8_t* ga = gA + kt * BKB;
        const uint8_t* gb = gB + kt * BKB;
        uint8_t* la = &As[b][t * 16];
        uint8_t* lb = &Bs[b][t * 16];
        #pragma unroll
        for (int c = 0; c < 4; ++c) {
            __builtin_amdgcn_global_load_lds((AS1 void*)(ga + (size_t)c * 32 * DIMK),
                                             (AS3 void*)(la + c * 4096), 16, 0, 0);
            __builtin_amdgcn_global_load_lds((AS1 void*)(gb + (size_t)c * 32 * DIMK),
                                             (AS3 void*)(lb + c * 4096), 16, 0, 0);
        }
    };

    auto read_frags = [&](int b, i32x8* af, i32x8* bg) {
        #pragma unroll
        for (int i = 0; i < 4; ++i)
            af[i] = ld_frag(&As[b][wm * 64 * BKB + roff[i]], c_lo, c_hi);
        #pragma unroll
        for (int i = 0; i < 4; ++i)
            bg[i] = ld_frag(&Bs[b][wn * 64 * BKB + roff[i]], c_lo, c_hi);
    };

    // swapped operands: A = bg[j] (x1 rows -> out-col in reg dim),
    //                   B = af[i] (x rows -> out-row in lane&15 dim)
    auto do_mfma = [&](const i32x8* af, const i32x8* bg) {
        #pragma unroll
        for (int j = 0; j < 4; ++j)
            #pragma unroll
            for (int i = 0; i < 4; ++i)
                acc[j][i] = __builtin_amdgcn_mfma_scale_f32_16x16x128_f8f6f4(
                    bg[j], af[i], acc[j][i],
                    0, 0,                    // cbsz=0 (fp8 e4m3), blgp=0 (fp8 e4m3)
                    0, 0x7F7F7F7F,           // opselA, scaleA (e8m0 127 = 2^0)
                    0, 0x7F7F7F7F);          // opselB, scaleB
    };

    i32x8 af[4], bg[4];

    stage(0, 0);
    stage(1, 1);                           // 16 outstanding

    // kt = 0
    WAITV(8); BAR();
    read_frags(0, af, bg);
    WAITL(); BAR();
    stage(2, 0);
    do_mfma(af, bg);

    // kt = 1
    WAITV(8); BAR();
    read_frags(1, af, bg);
    WAITL(); BAR();
    stage(3, 1);
    do_mfma(af, bg);

    // kt = 2
    WAITV(8); BAR();
    read_frags(0, af, bg);
    do_mfma(af, bg);

    // kt = 3
    WAITV(0); BAR();
    read_frags(1, af, bg);
    do_mfma(af, bg);

    // epilogue (transposed acc): out-row = bm*128+wm*64+tm*16+lrow,
    // out-col base = bn*128+wn*64+tn*16+(lane>>4)*4, reg r -> col base + r.
    const int orow = bm * BM + wm * 64 + lrow;
    const int ocol = bn * BN + wn * 64 + q * 4;
    float xs[4];
    f32x4 x1v[4];
    #pragma unroll
    for (int tm = 0; tm < 4; ++tm) xs[tm] = xsq[orow + tm * 16];
    #pragma unroll
    for (int tn = 0; tn < 4; ++tn) x1v[tn] = *(const f32x4*)&x1sq[ocol + tn * 16];

    #pragma unroll
    for (int tm = 0; tm < 4; ++tm) {
        float* orow_p = out + (size_t)(orow + tm * 16) * NROWS;
        #pragma unroll
        for (int tn = 0; tn < 4; ++tn) {
            f32x4 a = acc[tn][tm];
            f32x4 ev;
            #pragma unroll
            for (int r = 0; r < 4; ++r) {
                float d = fmaxf(xs[tm] + x1v[tn][r] - 2.0f * a[r], 0.0f);
                ev[r] = __expf(-d);
            }
            *(f32x4*)(orow_p + ocol + tn * 16) = ev;   // normal (L2 write-back) store
        }
    }
}

// Fallback GEMM (ws too small for fp8 copies): inline fp32->bf16 cast staging.
__global__ __launch_bounds__(256) void rbf_mfma_inline(
    const float* __restrict__ X, const float* __restrict__ X1,
    const float* __restrict__ xsq, const float* __restrict__ x1sq,
    float* __restrict__ out)
{
    __shared__ uint16_t As[BM * 32];
    __shared__ uint16_t Bs[BN * 32];

    const int t    = threadIdx.x;
    const int bm   = blockIdx.x;
    const int bn   = blockIdx.y;
    const int lane = t & 63;
    const int w    = t >> 6;
    const int wm   = w >> 1;
    const int wn   = w & 1;

    f32x4 acc[4][4];
    #pragma unroll
    for (int i = 0; i < 4; ++i)
        #pragma unroll
        for (int j = 0; j < 4; ++j)
            acc[i][j] = f32x4{0.f, 0.f, 0.f, 0.f};

    const int lrow = lane & 15;
    const int kq   = (lane >> 4) * 8;
    int aoff[4], boff[4];
    #pragma unroll
    for (int i = 0; i < 4; ++i) {
        aoff[i] = (wm * 64 + i * 16 + lrow) * 32 + kq;
        boff[i] = (wn * 64 + i * 16 + lrow) * 32 + kq;
    }

    #pragma unroll 1
    for (int kt = 0; kt < DIMK / 32; ++kt) {
        #pragma unroll
        for (int i = 0; i < 4; ++i) {
            const int g   = t + i * 256;
            const int row = g >> 3;
            const int c4  = (g & 7) * 4;
            float4 va = *(const float4*)&X [(size_t)(bm * BM + row) * DIMK + kt * 32 + c4];
            float4 vb = *(const float4*)&X1[(size_t)(bn * BN + row) * DIMK + kt * 32 + c4];
            uint2 pa, pb;
            pa.x = f2bf(va.x) | (f2bf(va.y) << 16);
            pa.y = f2bf(va.z) | (f2bf(va.w) << 16);
            pb.x = f2bf(vb.x) | (f2bf(vb.y) << 16);
            pb.y = f2bf(vb.z) | (f2bf(vb.w) << 16);
            *(uint2*)&As[g * 4] = pa;
            *(uint2*)&Bs[g * 4] = pb;
        }
        __syncthreads();

        bf16x8 af[4], bg[4];
        #pragma unroll
        for (int i = 0; i < 4; ++i) af[i] = *(const bf16x8*)&As[aoff[i]];
        #pragma unroll
        for (int i = 0; i < 4; ++i) bg[i] = *(const bf16x8*)&Bs[boff[i]];
        #pragma unroll
        for (int i = 0; i < 4; ++i)
            #pragma unroll
            for (int j = 0; j < 4; ++j)
                acc[i][j] = __builtin_amdgcn_mfma_f32_16x16x32_bf16(af[i], bg[j], acc[i][j], 0, 0, 0);
        __syncthreads();
    }

    const int row0 = bm * BM + wm * 64 + (lane >> 4) * 4;
    const int col0 = bn * BN + wn * 64 + lrow;
    float xs[4][4], x1s[4];
    #pragma unroll
    for (int tm = 0; tm < 4; ++tm)
        #pragma unroll
        for (int r = 0; r < 4; ++r) xs[tm][r] = xsq[row0 + tm * 16 + r];
    #pragma unroll
    for (int tn = 0; tn < 4; ++tn) x1s[tn] = x1sq[col0 + tn * 16];

    #pragma unroll
    for (int tm = 0; tm < 4; ++tm)
        #pragma unroll
        for (int tn = 0; tn < 4; ++tn)
            #pragma unroll
            for (int r = 0; r < 4; ++r) {
                const int row = row0 + tm * 16 + r;
                const int col = col0 + tn * 16;
                float d = xs[tm][r] + x1s[tn] - 2.0f * acc[tm][tn][r];
                d = fmaxf(d, 0.0f);
                out[(size_t)row * NROWS + col] = __expf(-d);
            }
}

// ------------------------------------------------------------------ launch ---
extern "C" void kernel_launch(void* const* d_in, const int* in_sizes, int n_in,
                              void* d_out, int out_size, void* d_ws, size_t ws_size,
                              hipStream_t stream)
{
    const float* x  = (const float*)d_in[0];
    const float* x1 = (const float*)d_in[1];
    float* out = (float*)d_out;

    const size_t f8_bytes  = (size_t)NROWS * DIMK;                       // 4 MB each
    const size_t need_full = 2 * f8_bytes + 2 * (size_t)NROWS * sizeof(float);

    dim3 gridG(NROWS / BM, NROWS / BN);   // 64 x 64 blocks

    if (ws_size >= need_full) {
        uint8_t* xf   = (uint8_t*)d_ws;
        uint8_t* x1f  = xf + f8_bytes;
        float*   xsq  = (float*)((char*)d_ws + 2 * f8_bytes);
        float*   x1sq = xsq + NROWS;
        precast_fp8<<<dim3(NROWS / 4, 2), 256, 0, stream>>>(x, x1, xf, x1f, xsq, x1sq);
        rbf_mfma_mxfp8<<<gridG, 256, 0, stream>>>(xf, x1f, xsq, x1sq, out);
    } else {
        float* xsq  = (float*)d_ws;       // 64 KB fallback
        float* x1sq = xsq + NROWS;
        norms_only<<<dim3(NROWS, 2), 256, 0, stream>>>(x, x1, xsq, x1sq);
        rbf_mfma_inline<<<gridG, 256, 0, stream>>>(x, x1, xsq, x1sq, out);
    }
}

// Round 8
// 301.423 us; speedup vs baseline: 1.0813x; 1.0352x over previous
//
#include <hip/hip_runtime.h>
#include <stdint.h>
#include <stddef.h>

// RBF kernel: out[i][j] = exp(-max(||x_i||^2 + ||x1_j||^2 - 2*x_i.x1_j, 0) / 1.0)
// N = M = 8192, K = 512, fp32 in/out.
//
// Round 8 = Round 7 + full-cache-line store epilogue (single variable).
// Theory: all prior epilogues store 64B half-lines per wave-inst; if L2
// write-allocates on partial lines, output traffic doubles (268MB write +
// ~268MB read) == the stubborn ~70-85us GEMM. Fix: round-trip each wave's
// 16x64 fp32 sub-tile through a 4KB LDS scratch (buffer-0 region, dead after
// the kt=3 barrier) and re-map lanes so each global_store_dwordx4 covers
// 4 rows x 256B contiguous = 8 FULL 128B lines.

#define NROWS 8192
#define DIMK  512
#define BM    128
#define BN    128
#define BKB   128              // K-bytes (= elements) per fp8 tile
#define KT    (DIMK / BKB)     // 4

typedef __bf16 bf16x8 __attribute__((ext_vector_type(8)));
typedef int    i32x8  __attribute__((ext_vector_type(8)));
typedef int    i32x4  __attribute__((ext_vector_type(4)));
typedef float  f32x4  __attribute__((ext_vector_type(4)));

#define AS1 __attribute__((address_space(1)))
#define AS3 __attribute__((address_space(3)))

// raw waits/barrier — keep prefetch DMA in flight across barriers
#define WAITV(n) asm volatile("s_waitcnt vmcnt(" #n ")" ::: "memory")
#define WAITL()  asm volatile("s_waitcnt lgkmcnt(0)" ::: "memory")
#define BAR()    asm volatile("s_barrier" ::: "memory")

__device__ __forceinline__ uint32_t f2bf(float f) {
    uint32_t u = __float_as_uint(f);
    return (u + 0x7FFFu + ((u >> 16) & 1u)) >> 16;
}

// pack 4 floats -> 4 e4m3 bytes via HW converter (RNE, saturating)
__device__ __forceinline__ uint32_t pk_fp8x4(float a, float b, float c, float d) {
    int w = __builtin_amdgcn_cvt_pk_fp8_f32(a, b, 0, false);   // bytes 0,1
    w     = __builtin_amdgcn_cvt_pk_fp8_f32(c, d, w, true);    // bytes 2,3
    return (uint32_t)w;
}

// assemble a 32B MFMA fragment from two (swizzle-permuted) 16B LDS chunks
__device__ __forceinline__ i32x8 ld_frag(const uint8_t* base, int c_lo, int c_hi) {
    i32x4 lo = *(const i32x4*)(base + c_lo);
    i32x4 hi = *(const i32x4*)(base + c_hi);
    i32x8 r;
    r[0] = lo[0]; r[1] = lo[1]; r[2] = lo[2]; r[3] = lo[3];
    r[4] = hi[0]; r[5] = hi[1]; r[6] = hi[2]; r[7] = hi[3];
    return r;
}

// ---------------------------------------------------------------- precast ---
__global__ __launch_bounds__(256) void precast_fp8(
    const float* __restrict__ x, const float* __restrict__ x1,
    uint8_t* __restrict__ xf, uint8_t* __restrict__ x1f,
    float* __restrict__ xsq, float* __restrict__ x1sq)
{
    const int w    = threadIdx.x >> 6;
    const int lane = threadIdx.x & 63;
    const int row  = blockIdx.x * 4 + w;
    const float* src;
    uint8_t* dstb;
    float* dsts;
    if (blockIdx.y == 0) { src = x  + (size_t)row * DIMK; dstb = xf  + (size_t)row * DIMK; dsts = xsq  + row; }
    else                 { src = x1 + (size_t)row * DIMK; dstb = x1f + (size_t)row * DIMK; dsts = x1sq + row; }

    float4 v0 = ((const float4*)src)[lane * 2];
    float4 v1 = ((const float4*)src)[lane * 2 + 1];
    float s = v0.x * v0.x + v0.y * v0.y + v0.z * v0.z + v0.w * v0.w
            + v1.x * v1.x + v1.y * v1.y + v1.z * v1.z + v1.w * v1.w;

    uint2 p;
    p.x = pk_fp8x4(v0.x, v0.y, v0.z, v0.w);
    p.y = pk_fp8x4(v1.x, v1.y, v1.z, v1.w);
    ((uint2*)dstb)[lane] = p;

    #pragma unroll
    for (int off = 32; off > 0; off >>= 1) s += __shfl_down(s, off);
    if (lane == 0) *dsts = s;
}

// norms only (fallback path)
__global__ __launch_bounds__(256) void norms_only(
    const float* __restrict__ x, const float* __restrict__ x1,
    float* __restrict__ xsq, float* __restrict__ x1sq)
{
    const int row = blockIdx.x;
    const float* src = (blockIdx.y == 0) ? x + (size_t)row * DIMK : x1 + (size_t)row * DIMK;
    float* dsts      = (blockIdx.y == 0) ? xsq + row : x1sq + row;
    const int t = threadIdx.x;
    float2 v = ((const float2*)src)[t];
    float s = v.x * v.x + v.y * v.y;
    #pragma unroll
    for (int off = 32; off > 0; off >>= 1) s += __shfl_down(s, off);
    __shared__ float red[4];
    if ((t & 63) == 0) red[t >> 6] = s;
    __syncthreads();
    if (t == 0) *dsts = red[0] + red[1] + red[2] + red[3];
}

// ------------------------------------------- main GEMM (MX-fp8, pipelined) ---
// LDS map (single array; compiler can't reorder): [0,16K)=A buf0,
// [16K,32K)=A buf1, [32K,48K)=B buf0, [48K,64K)=B buf1.
// Epilogue scratch reuses [0,16K) (A buf0): last read at kt=2, and every
// wave has passed the kt=3 vmcnt(0)+barrier before any scratch write.
//
// Wait ladder (8 DMA loads per stage, vmcnt completes in order — m135):
//   prologue: stage(0->b0), stage(1->b1)      [16 outstanding]
//   kt=0: vmcnt(8)+bar | reads | lgkm+bar | stage(2->b0) | mfma
//   kt=1: vmcnt(8)+bar | reads | lgkm+bar | stage(3->b1) | mfma
//   kt=2: vmcnt(8)+bar | reads |                         | mfma
//   kt=3: vmcnt(0)+bar | reads |                         | mfma
// Epilogue vmem strictly after the last wait so vmcnt bookkeeping is exact.
__global__ __launch_bounds__(256) void rbf_mfma_mxfp8(
    const uint8_t* __restrict__ Xf, const uint8_t* __restrict__ X1f,
    const float* __restrict__ xsq, const float* __restrict__ x1sq,
    float* __restrict__ out)
{
    __shared__ uint8_t lds[65536];

    const int t    = threadIdx.x;
    const int bm   = blockIdx.x;
    const int bn   = blockIdx.y;
    const int lane = t & 63;
    const int w    = t >> 6;
    const int wm   = w >> 1;
    const int wn   = w & 1;

    const int srow   = t >> 3;                       // 0..31
    const int schunk = (t & 7) ^ (srow & 7);         // XOR-swizzled global chunk
    const uint8_t* gA = Xf  + (size_t)(bm * BM + srow) * DIMK + schunk * 16;
    const uint8_t* gB = X1f + (size_t)(bn * BN + srow) * DIMK + schunk * 16;

    f32x4 acc[4][4];   // acc[tn][tm]
    #pragma unroll
    for (int i = 0; i < 4; ++i)
        #pragma unroll
        for (int j = 0; j < 4; ++j)
            acc[i][j] = f32x4{0.f, 0.f, 0.f, 0.f};

    // Operand layout (A and B identical): row = lane&15, kbyte = q*32+0..31.
    // Staging swizzle: kbyte chunk c of row r lives at LDS chunk c^(r&7).
    const int lrow = lane & 15;
    const int q    = lane >> 4;
    const int s    = lrow & 7;
    const int c_lo = ((2 * q)     ^ s) * 16;
    const int c_hi = ((2 * q + 1) ^ s) * 16;
    int roff[4];
    #pragma unroll
    for (int i = 0; i < 4; ++i) roff[i] = (i * 16 + lrow) * BKB;

    auto stage = [&](int kt, int b) {
        const uint8_t* ga = gA + kt * BKB;
        const uint8_t* gb = gB + kt * BKB;
        uint8_t* la = &lds[b * 16384 + t * 16];
        uint8_t* lb = &lds[32768 + b * 16384 + t * 16];
        #pragma unroll
        for (int c = 0; c < 4; ++c) {
            __builtin_amdgcn_global_load_lds((AS1 void*)(ga + (size_t)c * 32 * DIMK),
                                             (AS3 void*)(la + c * 4096), 16, 0, 0);
            __builtin_amdgcn_global_load_lds((AS1 void*)(gb + (size_t)c * 32 * DIMK),
                                             (AS3 void*)(lb + c * 4096), 16, 0, 0);
        }
    };

    auto read_frags = [&](int b, i32x8* af, i32x8* bg) {
        const uint8_t* Ab = &lds[b * 16384 + wm * 64 * BKB];
        const uint8_t* Bb = &lds[32768 + b * 16384 + wn * 64 * BKB];
        #pragma unroll
        for (int i = 0; i < 4; ++i) af[i] = ld_frag(Ab + roff[i], c_lo, c_hi);
        #pragma unroll
        for (int i = 0; i < 4; ++i) bg[i] = ld_frag(Bb + roff[i], c_lo, c_hi);
    };

    // swapped operands: A = bg[tn] (x1 rows -> reg dim), B = af[tm] (x rows
    // -> lane&15 dim). Lane holds out-row = lrow, out-cols = q*4+reg.
    auto do_mfma = [&](const i32x8* af, const i32x8* bg) {
        #pragma unroll
        for (int j = 0; j < 4; ++j)
            #pragma unroll
            for (int i = 0; i < 4; ++i)
                acc[j][i] = __builtin_amdgcn_mfma_scale_f32_16x16x128_f8f6f4(
                    bg[j], af[i], acc[j][i],
                    0, 0,                    // cbsz=0 (fp8 e4m3), blgp=0 (fp8 e4m3)
                    0, 0x7F7F7F7F,           // opselA, scaleA (e8m0 127 = 2^0)
                    0, 0x7F7F7F7F);          // opselB, scaleB
    };

    i32x8 af[4], bg[4];

    stage(0, 0);
    stage(1, 1);                           // 16 outstanding

    // kt = 0
    WAITV(8); BAR();
    read_frags(0, af, bg);
    WAITL(); BAR();
    stage(2, 0);
    do_mfma(af, bg);

    // kt = 1
    WAITV(8); BAR();
    read_frags(1, af, bg);
    WAITL(); BAR();
    stage(3, 1);
    do_mfma(af, bg);

    // kt = 2
    WAITV(8); BAR();
    read_frags(0, af, bg);
    do_mfma(af, bg);

    // kt = 3
    WAITV(0); BAR();
    read_frags(1, af, bg);
    do_mfma(af, bg);

    // ------------------------------------------------------------ epilogue ---
    // Wave-private 4KB scratch in [0,16K): wave w at w*4096. Per tm, the wave
    // round-trips its 16x64 fp32 sub-tile through LDS so each global store
    // covers 4 rows x 256B contiguous (8 full 128B lines). XOR chunk swizzle
    // (lc ^ (row&7)) spreads both LDS phases over all 32 banks.
    // No barrier needed: scratch is wave-private; per-wave DS ops are ordered.
    const int orow_w = bm * BM + wm * 64;            // wave's out-row base
    const int ocol_w = bn * BN + wn * 64;            // wave's out-col base
    uint8_t* scr = &lds[w * 4096];

    // producer-side norms: row norm for this lane's out-row, col norms x4
    float xsl[4];
    f32x4 x1v[4];
    #pragma unroll
    for (int tm = 0; tm < 4; ++tm) xsl[tm] = xsq[orow_w + tm * 16 + lrow];
    #pragma unroll
    for (int tn = 0; tn < 4; ++tn) x1v[tn] = *(const f32x4*)&x1sq[ocol_w + tn * 16 + q * 4];

    // consumer-side lane mapping: 16 lanes per row, 4 rows per store inst
    const int crow = lane >> 4;          // 0..3 (row within a 4-row store)
    const int clc  = lane & 15;          // 16B chunk within the 64-col row

    #pragma unroll
    for (int tm = 0; tm < 4; ++tm) {
        // produce: value(row=lrow, col = tn*16 + q*4 + r)
        #pragma unroll
        for (int tn = 0; tn < 4; ++tn) {
            f32x4 a = acc[tn][tm];
            f32x4 ev;
            #pragma unroll
            for (int r = 0; r < 4; ++r) {
                float d = fmaxf(xsl[tm] + x1v[tn][r] - 2.0f * a[r], 0.0f);
                ev[r] = __expf(-d);
            }
            const int lc = tn * 4 + q;                         // logical chunk
            *(f32x4*)(scr + lrow * 256 + ((lc ^ s) * 16)) = ev;
        }
        // consume: 4 store insts, each 4 rows x 16 chunks = 1KB contiguous/row-group
        float* gbase = out + (size_t)(orow_w + tm * 16) * NROWS + ocol_w;
        #pragma unroll
        for (int si = 0; si < 4; ++si) {
            const int row = si * 4 + crow;
            f32x4 v = *(const f32x4*)(scr + row * 256 + (((clc) ^ (row & 7)) * 16));
            *(f32x4*)(gbase + (size_t)row * NROWS + clc * 4) = v;
        }
    }
}

// Fallback GEMM (ws too small for fp8 copies): inline fp32->bf16 cast staging.
__global__ __launch_bounds__(256) void rbf_mfma_inline(
    const float* __restrict__ X, const float* __restrict__ X1,
    const float* __restrict__ xsq, const float* __restrict__ x1sq,
    float* __restrict__ out)
{
    __shared__ uint16_t As[BM * 32];
    __shared__ uint16_t Bs[BN * 32];

    const int t    = threadIdx.x;
    const int bm   = blockIdx.x;
    const int bn   = blockIdx.y;
    const int lane = t & 63;
    const int w    = t >> 6;
    const int wm   = w >> 1;
    const int wn   = w & 1;

    f32x4 acc[4][4];
    #pragma unroll
    for (int i = 0; i < 4; ++i)
        #pragma unroll
        for (int j = 0; j < 4; ++j)
            acc[i][j] = f32x4{0.f, 0.f, 0.f, 0.f};

    const int lrow = lane & 15;
    const int kq   = (lane >> 4) * 8;
    int aoff[4], boff[4];
    #pragma unroll
    for (int i = 0; i < 4; ++i) {
        aoff[i] = (wm * 64 + i * 16 + lrow) * 32 + kq;
        boff[i] = (wn * 64 + i * 16 + lrow) * 32 + kq;
    }

    #pragma unroll 1
    for (int kt = 0; kt < DIMK / 32; ++kt) {
        #pragma unroll
        for (int i = 0; i < 4; ++i) {
            const int g   = t + i * 256;
            const int row = g >> 3;
            const int c4  = (g & 7) * 4;
            float4 va = *(const float4*)&X [(size_t)(bm * BM + row) * DIMK + kt * 32 + c4];
            float4 vb = *(const float4*)&X1[(size_t)(bn * BN + row) * DIMK + kt * 32 + c4];
            uint2 pa, pb;
            pa.x = f2bf(va.x) | (f2bf(va.y) << 16);
            pa.y = f2bf(va.z) | (f2bf(va.w) << 16);
            pb.x = f2bf(vb.x) | (f2bf(vb.y) << 16);
            pb.y = f2bf(vb.z) | (f2bf(vb.w) << 16);
            *(uint2*)&As[g * 4] = pa;
            *(uint2*)&Bs[g * 4] = pb;
        }
        __syncthreads();

        bf16x8 af[4], bg[4];
        #pragma unroll
        for (int i = 0; i < 4; ++i) af[i] = *(const bf16x8*)&As[aoff[i]];
        #pragma unroll
        for (int i = 0; i < 4; ++i) bg[i] = *(const bf16x8*)&Bs[boff[i]];
        #pragma unroll
        for (int i = 0; i < 4; ++i)
            #pragma unroll
            for (int j = 0; j < 4; ++j)
                acc[i][j] = __builtin_amdgcn_mfma_f32_16x16x32_bf16(af[i], bg[j], acc[i][j], 0, 0, 0);
        __syncthreads();
    }

    const int row0 = bm * BM + wm * 64 + (lane >> 4) * 4;
    const int col0 = bn * BN + wn * 64 + lrow;
    float xs[4][4], x1s[4];
    #pragma unroll
    for (int tm = 0; tm < 4; ++tm)
        #pragma unroll
        for (int r = 0; r < 4; ++r) xs[tm][r] = xsq[row0 + tm * 16 + r];
    #pragma unroll
    for (int tn = 0; tn < 4; ++tn) x1s[tn] = x1sq[col0 + tn * 16];

    #pragma unroll
    for (int tm = 0; tm < 4; ++tm)
        #pragma unroll
        for (int tn = 0; tn < 4; ++tn)
            #pragma unroll
            for (int r = 0; r < 4; ++r) {
                const int row = row0 + tm * 16 + r;
                const int col = col0 + tn * 16;
                float d = xs[tm][r] + x1s[tn] - 2.0f * acc[tm][tn][r];
                d = fmaxf(d, 0.0f);
                out[(size_t)row * NROWS + col] = __expf(-d);
            }
}

// ------------------------------------------------------------------ launch ---
extern "C" void kernel_launch(void* const* d_in, const int* in_sizes, int n_in,
                              void* d_out, int out_size, void* d_ws, size_t ws_size,
                              hipStream_t stream)
{
    const float* x  = (const float*)d_in[0];
    const float* x1 = (const float*)d_in[1];
    float* out = (float*)d_out;

    const size_t f8_bytes  = (size_t)NROWS * DIMK;                       // 4 MB each
    const size_t need_full = 2 * f8_bytes + 2 * (size_t)NROWS * sizeof(float);

    dim3 gridG(NROWS / BM, NROWS / BN);   // 64 x 64 blocks

    if (ws_size >= need_full) {
        uint8_t* xf   = (uint8_t*)d_ws;
        uint8_t* x1f  = xf + f8_bytes;
        float*   xsq  = (float*)((char*)d_ws + 2 * f8_bytes);
        float*   x1sq = xsq + NROWS;
        precast_fp8<<<dim3(NROWS / 4, 2), 256, 0, stream>>>(x, x1, xf, x1f, xsq, x1sq);
        rbf_mfma_mxfp8<<<gridG, 256, 0, stream>>>(xf, x1f, xsq, x1sq, out);
    } else {
        float* xsq  = (float*)d_ws;       // 64 KB fallback
        float* x1sq = xsq + NROWS;
        norms_only<<<dim3(NROWS, 2), 256, 0, stream>>>(x, x1, xsq, x1sq);
        rbf_mfma_inline<<<gridG, 256, 0, stream>>>(x, x1, xsq, x1sq, out);
    }
}